// Round 14
// baseline (222.085 us; speedup 1.0000x reference)
//
#include <hip/hip_runtime.h>
#include <hip/hip_bf16.h>
#include <math.h>

// Problem constants (fixed by the reference setup)
constexpr int B = 8;
constexpr int V = 262144;
constexpr int J = 64;
constexpr int K = 4;
constexpr int G = 2048;
constexpr int L = 8;
constexpr int E = 1835008;
constexpr float EPS = 1e-8f;
constexpr int PT8 = 1024;      // posed8 block size (16 waves, 1 block/CU)
constexpr int NB2 = 256;       // fine buckets (1024 vertices each)
constexpr int VB2 = V / NB2;   // 1024
constexpr int PBLK = 256;      // partition blocks
constexpr int EPP = E / PBLK;  // 7168 edges per partition block
constexpr int CHK = 4096;      // lap_sorted chunk size (edges)
// posed8 LDS layout (u32 units): node dbuf 2*12288, jqd dbuf 2*512
constexpr int NODE_U2 = G * 3;        // 6144 uint2 per buffer
constexpr int JQ_OFF = 4 * NODE_U2;   // u32 offset of jqd area = 24576
constexpr int LDS_U32 = 2 * G * 6 + 2 * 512;  // 25600 u32 = 102400 B

__device__ inline unsigned bf16bits(float x) {
  unsigned u = __float_as_uint(x);
  return (u + 0x7fffu + ((u >> 16) & 1u)) >> 16;  // round-to-nearest-even
}
__device__ inline float bflo(unsigned u) { return __uint_as_float(u << 16); }
__device__ inline float bfhi(unsigned u) {
  return __uint_as_float(u & 0xffff0000u);
}

// ---------------------------------------------------------------------------
// Kernel 0: per (b,j) normalized joint quat + dual part jd = 0.5*qmul((0,t),q)
// ---------------------------------------------------------------------------
__global__ __launch_bounds__(256) void jqd_kernel(
    const float* __restrict__ jquat, const float* __restrict__ jtrans,
    float* __restrict__ ws) {
  int i = blockIdx.x * blockDim.x + threadIdx.x;
  if (i >= B * J) return;
  float qw = jquat[i * 4 + 0];
  float qx = jquat[i * 4 + 1];
  float qy = jquat[i * 4 + 2];
  float qz = jquat[i * 4 + 3];
  float inv = 1.0f / (sqrtf(qw * qw + qx * qx + qy * qy + qz * qz) + EPS);
  qw *= inv; qx *= inv; qy *= inv; qz *= inv;
  float tx = jtrans[i * 3 + 0];
  float ty = jtrans[i * 3 + 1];
  float tz = jtrans[i * 3 + 2];
  float dw = -0.5f * (tx * qx + ty * qy + tz * qz);
  float dx = 0.5f * (qw * tx + (ty * qz - tz * qy));
  float dy = 0.5f * (qw * ty + (tz * qx - tx * qz));
  float dz = 0.5f * (qw * tz + (tx * qy - ty * qx));
  float* o = ws + (size_t)i * 8;
  o[0] = qw; o[1] = qx; o[2] = qy; o[3] = qz;
  o[4] = dw; o[5] = dx; o[6] = dy; o[7] = dz;
}

// ---------------------------------------------------------------------------
// Kernel 0b: per (b,g) affine transform, bf16-packed: 12 bf16 = 6 u32 = 24 B.
// warped = M*p + T, T = gp + nt - M*gp.
// Pair order: (m00,m01)(m02,tx)(m10,m11)(m12,ty)(m20,m21)(m22,tz).
// ---------------------------------------------------------------------------
__global__ __launch_bounds__(256) void nmat16_kernel(
    const float* __restrict__ npos, const float* __restrict__ nquat,
    const float* __restrict__ ntrans, unsigned* __restrict__ nmt16) {
  int i = blockIdx.x * blockDim.x + threadIdx.x;
  if (i >= B * G) return;
  int g = i & (G - 1);
  float4 q = *reinterpret_cast<const float4*>(nquat + (size_t)i * 4);
  float qw = q.x, qx = q.y, qy = q.z, qz = q.w;
  float inv = 1.0f / (sqrtf(qw * qw + qx * qx + qy * qy + qz * qz) + EPS);
  qw *= inv; qx *= inv; qy *= inv; qz *= inv;
  float xx = qx * qx, yy = qy * qy, zz = qz * qz;
  float xy = qx * qy, xz = qx * qz, yz = qy * qz;
  float wx = qw * qx, wy = qw * qy, wz = qw * qz;
  float m00 = 1.f - 2.f * (yy + zz), m01 = 2.f * (xy - wz), m02 = 2.f * (xz + wy);
  float m10 = 2.f * (xy + wz), m11 = 1.f - 2.f * (xx + zz), m12 = 2.f * (yz - wx);
  float m20 = 2.f * (xz - wy), m21 = 2.f * (yz + wx), m22 = 1.f - 2.f * (xx + yy);
  float gx = npos[g * 3 + 0], gy = npos[g * 3 + 1], gz = npos[g * 3 + 2];
  float tx = ntrans[(size_t)i * 3 + 0] + gx - (m00 * gx + m01 * gy + m02 * gz);
  float ty = ntrans[(size_t)i * 3 + 1] + gy - (m10 * gx + m11 * gy + m12 * gz);
  float tz = ntrans[(size_t)i * 3 + 2] + gz - (m20 * gx + m21 * gy + m22 * gz);
  unsigned* o = nmt16 + (size_t)i * 6;
  o[0] = bf16bits(m00) | (bf16bits(m01) << 16);
  o[1] = bf16bits(m02) | (bf16bits(tx) << 16);
  o[2] = bf16bits(m10) | (bf16bits(m11) << 16);
  o[3] = bf16bits(m12) | (bf16bits(ty) << 16);
  o[4] = bf16bits(m20) | (bf16bits(m21) << 16);
  o[5] = bf16bits(m22) | (bf16bits(tz) << 16);
}

// ---------------------------------------------------------------------------
// posed8 — register-double-buffered LDS staging (node table + jqd table).
// 1024 threads, 256 blocks (1/CU), 100 KB dynamic LDS.
// Node planes: LDS uint2 index = buf*6144 + wp*2048 + g (bank-pair = g%16).
// jqd dense:   u32 offset JQ_OFF + buf*512 + j*8 (+w), read as float4.
// Stage loads for batch b+1 are issued BEFORE computing batch b (T14).
// mode: 0 = write pvm16, 2 = no pvm16 + zero lap
// ---------------------------------------------------------------------------
__global__ __launch_bounds__(PT8) void posed8_kernel(
    const float* __restrict__ tv, const float* __restrict__ sw_in,
    const float* __restrict__ lw_in, const int* __restrict__ sidx,
    const int* __restrict__ lidx, const unsigned* __restrict__ nmt16,
    const float* __restrict__ jq, float* __restrict__ out,
    unsigned* __restrict__ pvm16, int mode) {
  extern __shared__ unsigned sm8[];
  uint2* lds2 = reinterpret_cast<uint2*>(sm8);
  int t = threadIdx.x;
  int v = blockIdx.x * PT8 + t;

  float px = tv[(size_t)v * 3 + 0];
  float py = tv[(size_t)v * 3 + 1];
  float pz = tv[(size_t)v * 3 + 2];

  int4 si = *reinterpret_cast<const int4*>(sidx + (size_t)v * 4);
  float4 swv = *reinterpret_cast<const float4*>(sw_in + (size_t)v * 4);
  int4 li0 = *reinterpret_cast<const int4*>(lidx + (size_t)v * 8);
  int4 li1 = *reinterpret_cast<const int4*>(lidx + (size_t)v * 8 + 4);
  float4 lw0 = *reinterpret_cast<const float4*>(lw_in + (size_t)v * 8);
  float4 lw1 = *reinterpret_cast<const float4*>(lw_in + (size_t)v * 8 + 4);

  float sinv = 1.0f / (swv.x + swv.y + swv.z + swv.w + EPS);
  float swn[K] = {swv.x * sinv, swv.y * sinv, swv.z * sinv, swv.w * sinv};
  int sj[K] = {si.x, si.y, si.z, si.w};

  float linv =
      1.0f / (lw0.x + lw0.y + lw0.z + lw0.w + lw1.x + lw1.y + lw1.z + lw1.w + EPS);
  float lwn[L] = {lw0.x * linv, lw0.y * linv, lw0.z * linv, lw0.w * linv,
                  lw1.x * linv, lw1.y * linv, lw1.z * linv, lw1.w * linv};
  int gi[L] = {li0.x, li0.y, li0.z, li0.w, li1.x, li1.y, li1.z, li1.w};

  constexpr size_t LAPOFF = (size_t)B * V * 3;
  unsigned pk[2 * B];

  // register staging buffers
  uint2 stA[6];
  uint2 stJ;

  // prologue: issue loads for batch 0
  {
    const uint2* src = reinterpret_cast<const uint2*>(nmt16);
#pragma unroll
    for (int k = 0; k < 6; ++k) stA[k] = src[t + k * PT8];
    if (t < 256) stJ = reinterpret_cast<const uint2*>(jq)[t];
  }

  for (int b = 0; b < B; ++b) {
    int buf = b & 1;
    __syncthreads();  // buf's readers (iteration b-2) are done
    // write staged registers into LDS
#pragma unroll
    for (int k = 0; k < 6; ++k) {
      int id = t + k * PT8;
      int g = id / 3;
      int wp = id - 3 * g;
      lds2[buf * NODE_U2 + wp * G + g] = stA[k];
    }
    if (t < 256)
      reinterpret_cast<uint2*>(sm8 + JQ_OFF + buf * 512)[t] = stJ;
    // issue loads for batch b+1 (land during compute below)
    if (b < B - 1) {
      const uint2* src =
          reinterpret_cast<const uint2*>(nmt16) + (size_t)(b + 1) * (G * 3);
#pragma unroll
      for (int k = 0; k < 6; ++k) stA[k] = src[t + k * PT8];
      if (t < 256)
        stJ = reinterpret_cast<const uint2*>(jq)[(size_t)(b + 1) * 256 + t];
    }
    __syncthreads();  // LDS writes visible

    // ---- v_eg = sum_l lw * (M p + T); 3 plane b64 reads per link ----
    const uint2* nb = lds2 + buf * NODE_U2;
    float ex = 0.f, ey = 0.f, ez = 0.f;
#pragma unroll
    for (int l = 0; l < L; ++l) {
      int g = gi[l];
      uint2 u0 = nb[g];
      uint2 u1 = nb[G + g];
      uint2 u2 = nb[2 * G + g];
      float w = lwn[l];
      ex += w * (bflo(u0.x) * px + bfhi(u0.x) * py + bflo(u0.y) * pz + bfhi(u0.y));
      ey += w * (bflo(u1.x) * px + bfhi(u1.x) * py + bflo(u1.y) * pz + bfhi(u1.y));
      ez += w * (bflo(u2.x) * px + bfhi(u2.x) * py + bflo(u2.y) * pz + bfhi(u2.y));
    }

    // ---- joint dual-quat blend from LDS jqd table ----
    const float* jbase = reinterpret_cast<const float*>(sm8 + JQ_OFF + buf * 512);
    float rbw = 0.f, rbx = 0.f, rby = 0.f, rbz = 0.f;
    float dbw = 0.f, dbx = 0.f, dby = 0.f, dbz = 0.f;
    float r0w = 0.f, r0x = 0.f, r0y = 0.f, r0z = 0.f;
#pragma unroll
    for (int k = 0; k < K; ++k) {
      const float* eptr = jbase + sj[k] * 8;
      float4 qf = *reinterpret_cast<const float4*>(eptr);
      float4 df = *reinterpret_cast<const float4*>(eptr + 4);
      float qw = qf.x, qx = qf.y, qy = qf.z, qz = qf.w;
      if (k == 0) { r0w = qw; r0x = qx; r0y = qy; r0z = qz; }
      float dotr = qw * r0w + qx * r0x + qy * r0y + qz * r0z;
      float s = (dotr >= 0.0f) ? swn[k] : -swn[k];
      rbw += s * qw; rbx += s * qx; rby += s * qy; rbz += s * qz;
      dbw += s * df.x; dbx += s * df.y; dby += s * df.z; dbz += s * df.w;
    }
    float ninv = 1.0f / (sqrtf(rbw * rbw + rbx * rbx + rby * rby + rbz * rbz) + EPS);
    rbw *= ninv; rbx *= ninv; rby *= ninv; rbz *= ninv;
    dbw *= ninv; dbx *= ninv; dby *= ninv; dbz *= ninv;

    float txx = 2.0f * (rbw * dbx - dbw * rbx + (rby * dbz - rbz * dby));
    float tyy = 2.0f * (rbw * dby - dbw * rby + (rbz * dbx - rbx * dbz));
    float tzz = 2.0f * (rbw * dbz - dbw * rbz + (rbx * dby - rby * dbx));

    float cx = rby * ez - rbz * ey + rbw * ex;
    float cy = rbz * ex - rbx * ez + rbw * ey;
    float cz = rbx * ey - rby * ex + rbw * ez;
    float ox = ex + 2.0f * (rby * cz - rbz * cy) + txx;
    float oy = ey + 2.0f * (rbz * cx - rbx * cz) + tyy;
    float oz = ez + 2.0f * (rbx * cy - rby * cx) + tzz;

    size_t o = ((size_t)b * V + v) * 3;
    out[o + 0] = ox; out[o + 1] = oy; out[o + 2] = oz;
    pk[b * 2 + 0] = bf16bits(ox) | (bf16bits(oy) << 16);
    pk[b * 2 + 1] = bf16bits(oz);
    if (mode == 2) {
      out[LAPOFF + o + 0] = 0.f;
      out[LAPOFF + o + 1] = 0.f;
      out[LAPOFF + o + 2] = 0.f;
    }
  }

  if (mode == 0) {
    uint4* dst = reinterpret_cast<uint4*>(pvm16 + (size_t)v * 16);
    dst[0] = make_uint4(pk[0], pk[1], pk[2], pk[3]);
    dst[1] = make_uint4(pk[4], pk[5], pk[6], pk[7]);
    dst[2] = make_uint4(pk[8], pk[9], pk[10], pk[11]);
    dst[3] = make_uint4(pk[12], pk[13], pk[14], pk[15]);
  }
}

// ---------------------------------------------------------------------------
// 256-way edge partition (single level). Bucket = st >> 10 (1024 verts each).
// Payload packs s_local(10b) | d(18b) into one int + weight.
// ---------------------------------------------------------------------------
__global__ __launch_bounds__(256) void cnt256_kernel(const int* __restrict__ st,
                                                     int* __restrict__ bcnt) {
  __shared__ int h[NB2];
  int blk = blockIdx.x, t = threadIdx.x;
  h[t] = 0;
  __syncthreads();
  int e0 = blk * EPP;
  for (int i = e0 + t; i < e0 + EPP; i += 256) atomicAdd(&h[st[i] >> 10], 1);
  __syncthreads();
  bcnt[t * PBLK + blk] = h[t];  // bucket-major
}

// scan of bcnt[NB2*PBLK]: block g scans bucket g's 256 entries
__global__ __launch_bounds__(256) void scanA_kernel(const int* __restrict__ in,
                                                    int* __restrict__ out,
                                                    int* __restrict__ bs) {
  __shared__ int s[256];
  int t = threadIdx.x;
  int i = blockIdx.x * 256 + t;
  int x = in[i];
  s[t] = x;
  __syncthreads();
  for (int off = 1; off < 256; off <<= 1) {
    int v = (t >= off) ? s[t - off] : 0;
    __syncthreads();
    s[t] += v;
    __syncthreads();
  }
  out[i] = s[t] - x;
  if (t == 255) bs[blockIdx.x] = s[t];
}

__global__ __launch_bounds__(256) void scanB_kernel(int* __restrict__ bs) {
  __shared__ int s[256];
  int t = threadIdx.x;
  int x = bs[t];
  s[t] = x;
  __syncthreads();
  for (int off = 1; off < 256; off <<= 1) {
    int v = (t >= off) ? s[t - off] : 0;
    __syncthreads();
    s[t] += v;
    __syncthreads();
  }
  bs[t] = s[t] - x;
}

__global__ __launch_bounds__(256) void scanC_kernel(int* __restrict__ out,
                                                    const int* __restrict__ bs) {
  out[blockIdx.x * 256 + threadIdx.x] += bs[blockIdx.x];
}

__global__ __launch_bounds__(256) void part256_kernel(
    const int* __restrict__ st, const int* __restrict__ ed,
    const float* __restrict__ w, const int* __restrict__ boff2,
    int2* __restrict__ ewB) {
  __shared__ int lbase[NB2];
  __shared__ int lcur[NB2];
  int blk = blockIdx.x, t = threadIdx.x;
  lbase[t] = boff2[t * PBLK + blk];
  lcur[t] = 0;
  __syncthreads();
  int e0 = blk * EPP;
  for (int i = e0 + t; i < e0 + EPP; i += 256) {
    int s = st[i];
    int b = s >> 10;
    int pos = lbase[b] + atomicAdd(&lcur[b], 1);
    ewB[pos] = make_int2(((s & 1023) << 18) | ed[i], __float_as_int(w[i]));
  }
}

// ---------------------------------------------------------------------------
// lap_sorted: one 1024-thread block per 1024-vertex bucket. Per 4096-edge
// chunk: LDS counting sort by s_local, then thread t (= vertex t) walks its
// row, random-reads pvm16 (1x64 B line/edge), accumulates in registers.
// ---------------------------------------------------------------------------
__global__ __launch_bounds__(1024) void lap_sorted_kernel(
    const int2* __restrict__ ewB, const int* __restrict__ boff2,
    const unsigned* __restrict__ pvm16, float* __restrict__ lap) {
  __shared__ int2 eL[CHK];     // 32 KB sorted chunk
  __shared__ int rs[VB2];      // hist -> inclusive -> exclusive rowstart
  __shared__ int cur[VB2];     // scatter cursors
  int p = blockIdx.x, t = threadIdx.x;
  int beg = boff2[p * PBLK];
  int end = (p < NB2 - 1) ? boff2[(p + 1) * PBLK] : E;

  float acc[24];
#pragma unroll
  for (int i = 0; i < 24; ++i) acc[i] = 0.f;

  for (int cbeg = beg; cbeg < end; cbeg += CHK) {
    int cnt = min(CHK, end - cbeg);
    rs[t] = 0;
    __syncthreads();

    int2 er[CHK / 1024];
#pragma unroll
    for (int j = 0; j < CHK / 1024; ++j) {
      int idx = j * 1024 + t;
      if (idx < cnt) {
        er[j] = ewB[cbeg + idx];
        atomicAdd(&rs[((unsigned)er[j].x) >> 18], 1);
      }
    }
    __syncthreads();

    int x = rs[t];
    for (int off = 1; off < VB2; off <<= 1) {
      int v = (t >= off) ? rs[t - off] : 0;
      __syncthreads();
      rs[t] += v;
      __syncthreads();
    }
    int excl = rs[t] - x;
    __syncthreads();
    rs[t] = excl;
    cur[t] = excl;
    __syncthreads();

#pragma unroll
    for (int j = 0; j < CHK / 1024; ++j) {
      int idx = j * 1024 + t;
      if (idx < cnt) {
        int sl = ((unsigned)er[j].x) >> 18;
        int pos = atomicAdd(&cur[sl], 1);
        eL[pos] = er[j];
      }
    }
    __syncthreads();

    int rbeg = rs[t];
    int rend = (t < VB2 - 1) ? rs[t + 1] : cnt;
    for (int j = rbeg; j < rend; ++j) {
      int2 ew = eL[j];
      float w = __int_as_float(ew.y);
      int d = ew.x & 0x3ffff;
      const uint4* q = reinterpret_cast<const uint4*>(pvm16 + (size_t)d * 16);
      uint4 q0 = q[0], q1 = q[1], q2 = q[2], q3 = q[3];
      unsigned u[16] = {q0.x, q0.y, q0.z, q0.w, q1.x, q1.y, q1.z, q1.w,
                        q2.x, q2.y, q2.z, q2.w, q3.x, q3.y, q3.z, q3.w};
#pragma unroll
      for (int b = 0; b < B; ++b) {
        acc[b * 3 + 0] += w * bflo(u[2 * b]);
        acc[b * 3 + 1] += w * bfhi(u[2 * b]);
        acc[b * 3 + 2] += w * bflo(u[2 * b + 1]);
      }
    }
    __syncthreads();  // eL/rs reused next chunk
  }

  int v = p * VB2 + t;
#pragma unroll
  for (int b = 0; b < B; ++b) {
    size_t o = ((size_t)b * V + v) * 3;
    lap[o + 0] = acc[b * 3 + 0];
    lap[o + 1] = acc[b * 3 + 1];
    lap[o + 2] = acc[b * 3 + 2];
  }
}

// Tier-C fallback: per-edge atomic scatter.
__global__ __launch_bounds__(256) void lap_atomic_kernel(
    const float* __restrict__ lapw, const int* __restrict__ st,
    const int* __restrict__ ed, const float* __restrict__ posed,
    float* __restrict__ lap) {
  int e = blockIdx.x * blockDim.x + threadIdx.x;
  if (e >= E) return;
  float w = lapw[e];
  int s = st[e];
  int d = ed[e];
#pragma unroll
  for (int b = 0; b < B; ++b) {
    size_t pb = ((size_t)b * V + d) * 3;
    size_t ob = ((size_t)b * V + s) * 3;
    atomicAdd(&lap[ob + 0], w * posed[pb + 0]);
    atomicAdd(&lap[ob + 1], w * posed[pb + 1]);
    atomicAdd(&lap[ob + 2], w * posed[pb + 2]);
  }
}

extern "C" void kernel_launch(void* const* d_in, const int* in_sizes, int n_in,
                              void* d_out, int out_size, void* d_ws, size_t ws_size,
                              hipStream_t stream) {
  const float* tv    = (const float*)d_in[0];
  const float* jquat = (const float*)d_in[1];
  const float* jtran = (const float*)d_in[2];
  const float* sw    = (const float*)d_in[3];
  const float* npos  = (const float*)d_in[4];
  const float* nquat = (const float*)d_in[5];
  const float* ntran = (const float*)d_in[6];
  const float* lw    = (const float*)d_in[7];
  const float* lapw  = (const float*)d_in[8];
  const int*   sidx  = (const int*)d_in[9];
  const int*   lidx  = (const int*)d_in[10];
  const int*   lst   = (const int*)d_in[11];
  const int*   led   = (const int*)d_in[12];
  float* out = (float*)d_out;
  float* lap = out + (size_t)B * V * 3;

  // ---- workspace layout (all offsets 16 B aligned) ----
  float*    jqd   = (float*)d_ws;                       // 4096 f (16 KB)
  unsigned* nmt16 = (unsigned*)(jqd + 4096);            // B*G*6 u32 (384 KB)
  int*      bcnt  = (int*)(nmt16 + (size_t)B * G * 6);  // 65536 i (256 KB)
  int*      boff2 = bcnt + NB2 * PBLK;                  // 65536 i (256 KB)
  int*      bsum  = boff2 + NB2 * PBLK;                 // 256 i (+pad)
  int2*     ewB   = (int2*)(bsum + 256 + 60);           // E int2 (14.68 MB)
  unsigned* pvm16 = (unsigned*)(ewB + E);               // V*16 u32 (16.78 MB)
  size_t need = (size_t)((char*)(pvm16 + (size_t)V * 16) - (char*)d_ws);
  int tier = (ws_size >= need) ? 0 : 2;

  jqd_kernel<<<(B * J + 255) / 256, 256, 0, stream>>>(jquat, jtran, jqd);
  nmat16_kernel<<<(B * G + 255) / 256, 256, 0, stream>>>(npos, nquat, ntran,
                                                         nmt16);

  if (tier == 0) {
    cnt256_kernel<<<PBLK, 256, 0, stream>>>(lst, bcnt);
    scanA_kernel<<<NB2, 256, 0, stream>>>(bcnt, boff2, bsum);
    scanB_kernel<<<1, 256, 0, stream>>>(bsum);
    scanC_kernel<<<NB2, 256, 0, stream>>>(boff2, bsum);
    part256_kernel<<<PBLK, 256, 0, stream>>>(lst, led, lapw, boff2, ewB);
    posed8_kernel<<<V / PT8, PT8, LDS_U32 * sizeof(unsigned), stream>>>(
        tv, sw, lw, sidx, lidx, nmt16, jqd, out, pvm16, 0);
    lap_sorted_kernel<<<NB2, 1024, 0, stream>>>(ewB, boff2, pvm16, lap);
  } else {
    posed8_kernel<<<V / PT8, PT8, LDS_U32 * sizeof(unsigned), stream>>>(
        tv, sw, lw, sidx, lidx, nmt16, jqd, out, (unsigned*)jqd, 2);
    lap_atomic_kernel<<<E / 256, 256, 0, stream>>>(lapw, lst, led, out, lap);
  }
}

// Round 15
// 175.828 us; speedup vs baseline: 1.2631x; 1.2631x over previous
//
#include <hip/hip_runtime.h>
#include <hip/hip_bf16.h>
#include <math.h>

// Problem constants (fixed by the reference setup)
constexpr int B = 8;
constexpr int V = 262144;
constexpr int J = 64;
constexpr int K = 4;
constexpr int G = 2048;
constexpr int L = 8;
constexpr int E = 1835008;
constexpr float EPS = 1e-8f;
constexpr int PT5 = 1024;      // posed5 block size (16 waves, 1 block/CU)
constexpr int NB2 = 512;       // fine buckets (512 vertices each)
constexpr int VB2 = V / NB2;   // 512
constexpr int PBLK = 256;      // partition blocks
constexpr int EPP = E / PBLK;  // 7168 edges per partition block
constexpr int LT = 512;        // lap_sorted block size (8 waves, 4 blocks/CU)
constexpr int CHK = 2048;      // lap_sorted chunk size (edges)

__device__ inline unsigned bf16bits(float x) {
  unsigned u = __float_as_uint(x);
  return (u + 0x7fffu + ((u >> 16) & 1u)) >> 16;  // round-to-nearest-even
}
__device__ inline float bflo(unsigned u) { return __uint_as_float(u << 16); }
__device__ inline float bfhi(unsigned u) {
  return __uint_as_float(u & 0xffff0000u);
}

// ---------------------------------------------------------------------------
// Kernel 0: per (b,j) normalized joint quat + dual part jd = 0.5*qmul((0,t),q)
// ---------------------------------------------------------------------------
__global__ __launch_bounds__(256) void jqd_kernel(
    const float* __restrict__ jquat, const float* __restrict__ jtrans,
    float* __restrict__ ws) {
  int i = blockIdx.x * blockDim.x + threadIdx.x;
  if (i >= B * J) return;
  float qw = jquat[i * 4 + 0];
  float qx = jquat[i * 4 + 1];
  float qy = jquat[i * 4 + 2];
  float qz = jquat[i * 4 + 3];
  float inv = 1.0f / (sqrtf(qw * qw + qx * qx + qy * qy + qz * qz) + EPS);
  qw *= inv; qx *= inv; qy *= inv; qz *= inv;
  float tx = jtrans[i * 3 + 0];
  float ty = jtrans[i * 3 + 1];
  float tz = jtrans[i * 3 + 2];
  float dw = -0.5f * (tx * qx + ty * qy + tz * qz);
  float dx = 0.5f * (qw * tx + (ty * qz - tz * qy));
  float dy = 0.5f * (qw * ty + (tz * qx - tx * qz));
  float dz = 0.5f * (qw * tz + (tx * qy - ty * qx));
  float* o = ws + (size_t)i * 8;
  o[0] = qw; o[1] = qx; o[2] = qy; o[3] = qz;
  o[4] = dw; o[5] = dx; o[6] = dy; o[7] = dz;
}

// ---------------------------------------------------------------------------
// Kernel 0b: per (b,g) affine transform, packed [G][3]float4 per batch (f32).
// warped = M*p + T, T = gp + nt - M*gp. Row r = float4 {m_r0,m_r1,m_r2,t_r}.
// ---------------------------------------------------------------------------
__global__ __launch_bounds__(256) void nmat_kernel(
    const float* __restrict__ npos, const float* __restrict__ nquat,
    const float* __restrict__ ntrans, float* __restrict__ nmt) {
  int i = blockIdx.x * blockDim.x + threadIdx.x;
  if (i >= B * G) return;
  int g = i & (G - 1);
  float4 q = *reinterpret_cast<const float4*>(nquat + (size_t)i * 4);
  float qw = q.x, qx = q.y, qy = q.z, qz = q.w;
  float inv = 1.0f / (sqrtf(qw * qw + qx * qx + qy * qy + qz * qz) + EPS);
  qw *= inv; qx *= inv; qy *= inv; qz *= inv;
  float xx = qx * qx, yy = qy * qy, zz = qz * qz;
  float xy = qx * qy, xz = qx * qz, yz = qy * qz;
  float wx = qw * qx, wy = qw * qy, wz = qw * qz;
  float m00 = 1.f - 2.f * (yy + zz), m01 = 2.f * (xy - wz), m02 = 2.f * (xz + wy);
  float m10 = 2.f * (xy + wz), m11 = 1.f - 2.f * (xx + zz), m12 = 2.f * (yz - wx);
  float m20 = 2.f * (xz - wy), m21 = 2.f * (yz + wx), m22 = 1.f - 2.f * (xx + yy);
  float gx = npos[g * 3 + 0], gy = npos[g * 3 + 1], gz = npos[g * 3 + 2];
  float tx = ntrans[(size_t)i * 3 + 0] + gx - (m00 * gx + m01 * gy + m02 * gz);
  float ty = ntrans[(size_t)i * 3 + 1] + gy - (m10 * gx + m11 * gy + m12 * gz);
  float tz = ntrans[(size_t)i * 3 + 2] + gz - (m20 * gx + m21 * gy + m22 * gz);
  float4* o = reinterpret_cast<float4*>(nmt + (size_t)i * 12);
  o[0] = make_float4(m00, m01, m02, tx);
  o[1] = make_float4(m10, m11, m12, ty);
  o[2] = make_float4(m20, m21, m22, tz);
}

// ---------------------------------------------------------------------------
// posed5 — LDS-staged f32 node table, ds_read_b128 gathers. 1024 thr, 96 KB.
// (R11-proven structure.) mode: 0 = write pvm16, 2 = no pvm16 + zero lap
// ---------------------------------------------------------------------------
__global__ __launch_bounds__(PT5) void posed5_kernel(
    const float* __restrict__ tv, const float* __restrict__ sw_in,
    const float* __restrict__ lw_in, const int* __restrict__ sidx,
    const int* __restrict__ lidx, const float* __restrict__ nmt,
    const float* __restrict__ jqd, float* __restrict__ out,
    unsigned* __restrict__ pvm16, int mode) {
  extern __shared__ float4 sm4[];  // G*3 float4 = 98304 B
  int v = blockIdx.x * PT5 + threadIdx.x;

  float px = tv[(size_t)v * 3 + 0];
  float py = tv[(size_t)v * 3 + 1];
  float pz = tv[(size_t)v * 3 + 2];

  int4 si = *reinterpret_cast<const int4*>(sidx + (size_t)v * 4);
  float4 swv = *reinterpret_cast<const float4*>(sw_in + (size_t)v * 4);
  int4 li0 = *reinterpret_cast<const int4*>(lidx + (size_t)v * 8);
  int4 li1 = *reinterpret_cast<const int4*>(lidx + (size_t)v * 8 + 4);
  float4 lw0 = *reinterpret_cast<const float4*>(lw_in + (size_t)v * 8);
  float4 lw1 = *reinterpret_cast<const float4*>(lw_in + (size_t)v * 8 + 4);

  float sinv = 1.0f / (swv.x + swv.y + swv.z + swv.w + EPS);
  float swn[K] = {swv.x * sinv, swv.y * sinv, swv.z * sinv, swv.w * sinv};
  int sj[K] = {si.x, si.y, si.z, si.w};

  float linv =
      1.0f / (lw0.x + lw0.y + lw0.z + lw0.w + lw1.x + lw1.y + lw1.z + lw1.w + EPS);
  float lwn[L] = {lw0.x * linv, lw0.y * linv, lw0.z * linv, lw0.w * linv,
                  lw1.x * linv, lw1.y * linv, lw1.z * linv, lw1.w * linv};
  int gi[L] = {li0.x * 3, li0.y * 3, li0.z * 3, li0.w * 3,
               li1.x * 3, li1.y * 3, li1.z * 3, li1.w * 3};

  constexpr size_t LAPOFF = (size_t)B * V * 3;
  unsigned pk[2 * B];

  for (int b = 0; b < B; ++b) {
    __syncthreads();
    const float4* src = reinterpret_cast<const float4*>(nmt + (size_t)b * G * 12);
#pragma unroll
    for (int it = 0; it < (G * 3) / PT5; ++it) {
      int q = it * PT5 + threadIdx.x;
      sm4[q] = src[q];
    }
    __syncthreads();

    float ex = 0.f, ey = 0.f, ez = 0.f;
#pragma unroll
    for (int l = 0; l < L; ++l) {
      float4 r0 = sm4[gi[l] + 0];
      float4 r1 = sm4[gi[l] + 1];
      float4 r2 = sm4[gi[l] + 2];
      float w = lwn[l];
      ex += w * (r0.x * px + r0.y * py + r0.z * pz + r0.w);
      ey += w * (r1.x * px + r1.y * py + r1.z * pz + r1.w);
      ez += w * (r2.x * px + r2.y * py + r2.z * pz + r2.w);
    }

    float rbw = 0.f, rbx = 0.f, rby = 0.f, rbz = 0.f;
    float dbw = 0.f, dbx = 0.f, dby = 0.f, dbz = 0.f;
    float r0w = 0.f, r0x = 0.f, r0y = 0.f, r0z = 0.f;
#pragma unroll
    for (int k = 0; k < K; ++k) {
      const float* eptr = jqd + ((size_t)b * J + sj[k]) * 8;
      float4 qf = *reinterpret_cast<const float4*>(eptr);
      float4 df = *reinterpret_cast<const float4*>(eptr + 4);
      float qw = qf.x, qx = qf.y, qy = qf.z, qz = qf.w;
      if (k == 0) { r0w = qw; r0x = qx; r0y = qy; r0z = qz; }
      float dotr = qw * r0w + qx * r0x + qy * r0y + qz * r0z;
      float s = (dotr >= 0.0f) ? swn[k] : -swn[k];
      rbw += s * qw; rbx += s * qx; rby += s * qy; rbz += s * qz;
      dbw += s * df.x; dbx += s * df.y; dby += s * df.z; dbz += s * df.w;
    }
    float ninv = 1.0f / (sqrtf(rbw * rbw + rbx * rbx + rby * rby + rbz * rbz) + EPS);
    rbw *= ninv; rbx *= ninv; rby *= ninv; rbz *= ninv;
    dbw *= ninv; dbx *= ninv; dby *= ninv; dbz *= ninv;

    float txx = 2.0f * (rbw * dbx - dbw * rbx + (rby * dbz - rbz * dby));
    float tyy = 2.0f * (rbw * dby - dbw * rby + (rbz * dbx - rbx * dbz));
    float tzz = 2.0f * (rbw * dbz - dbw * rbz + (rbx * dby - rby * dbx));

    float cx = rby * ez - rbz * ey + rbw * ex;
    float cy = rbz * ex - rbx * ez + rbw * ey;
    float cz = rbx * ey - rby * ex + rbw * ez;
    float ox = ex + 2.0f * (rby * cz - rbz * cy) + txx;
    float oy = ey + 2.0f * (rbz * cx - rbx * cz) + tyy;
    float oz = ez + 2.0f * (rbx * cy - rby * cx) + tzz;

    size_t o = ((size_t)b * V + v) * 3;
    out[o + 0] = ox; out[o + 1] = oy; out[o + 2] = oz;
    pk[b * 2 + 0] = bf16bits(ox) | (bf16bits(oy) << 16);
    pk[b * 2 + 1] = bf16bits(oz);
    if (mode == 2) {
      out[LAPOFF + o + 0] = 0.f;
      out[LAPOFF + o + 1] = 0.f;
      out[LAPOFF + o + 2] = 0.f;
    }
  }

  if (mode == 0) {
    uint4* dst = reinterpret_cast<uint4*>(pvm16 + (size_t)v * 16);
    dst[0] = make_uint4(pk[0], pk[1], pk[2], pk[3]);
    dst[1] = make_uint4(pk[4], pk[5], pk[6], pk[7]);
    dst[2] = make_uint4(pk[8], pk[9], pk[10], pk[11]);
    dst[3] = make_uint4(pk[12], pk[13], pk[14], pk[15]);
  }
}

// ---------------------------------------------------------------------------
// 512-way edge partition. Bucket = st >> 9 (512 verts each).
// Payload packs s_local(9b) << 18 | d(18b) into one int + weight.
// ---------------------------------------------------------------------------
__global__ __launch_bounds__(256) void cnt512_kernel(const int* __restrict__ st,
                                                     int* __restrict__ bcnt) {
  __shared__ int h[NB2];
  int blk = blockIdx.x, t = threadIdx.x;
  h[t] = 0;
  h[t + 256] = 0;
  __syncthreads();
  int e0 = blk * EPP;
  for (int i = e0 + t; i < e0 + EPP; i += 256) atomicAdd(&h[st[i] >> 9], 1);
  __syncthreads();
  bcnt[t * PBLK + blk] = h[t];
  bcnt[(t + 256) * PBLK + blk] = h[t + 256];
}

// scanA: block g scans bucket g's 256 per-partition-block counts
__global__ __launch_bounds__(256) void scanA_kernel(const int* __restrict__ in,
                                                    int* __restrict__ out,
                                                    int* __restrict__ bs) {
  __shared__ int s[256];
  int t = threadIdx.x;
  int i = blockIdx.x * 256 + t;
  int x = in[i];
  s[t] = x;
  __syncthreads();
  for (int off = 1; off < 256; off <<= 1) {
    int v = (t >= off) ? s[t - off] : 0;
    __syncthreads();
    s[t] += v;
    __syncthreads();
  }
  out[i] = s[t] - x;
  if (t == 255) bs[blockIdx.x] = s[t];
}

// scanB: exclusive scan of NB2=512 bucket totals (one block, 512 thr)
__global__ __launch_bounds__(512) void scanB_kernel(int* __restrict__ bs) {
  __shared__ int s[NB2];
  int t = threadIdx.x;
  int x = bs[t];
  s[t] = x;
  __syncthreads();
  for (int off = 1; off < NB2; off <<= 1) {
    int v = (t >= off) ? s[t - off] : 0;
    __syncthreads();
    s[t] += v;
    __syncthreads();
  }
  bs[t] = s[t] - x;
}

__global__ __launch_bounds__(256) void scanC_kernel(int* __restrict__ out,
                                                    const int* __restrict__ bs) {
  out[blockIdx.x * 256 + threadIdx.x] += bs[blockIdx.x];
}

__global__ __launch_bounds__(256) void part512_kernel(
    const int* __restrict__ st, const int* __restrict__ ed,
    const float* __restrict__ w, const int* __restrict__ boff2,
    int2* __restrict__ ewB) {
  __shared__ int lbase[NB2];
  __shared__ int lcur[NB2];
  int blk = blockIdx.x, t = threadIdx.x;
  lbase[t] = boff2[t * PBLK + blk];
  lbase[t + 256] = boff2[(t + 256) * PBLK + blk];
  lcur[t] = 0;
  lcur[t + 256] = 0;
  __syncthreads();
  int e0 = blk * EPP;
  for (int i = e0 + t; i < e0 + EPP; i += 256) {
    int s = st[i];
    int b = s >> 9;
    int pos = lbase[b] + atomicAdd(&lcur[b], 1);
    ewB[pos] = make_int2(((s & 511) << 18) | ed[i], __float_as_int(w[i]));
  }
}

// ---------------------------------------------------------------------------
// lap_sorted: one 512-thread block per 512-vertex bucket (512 blocks =
// 4 blocks/CU = 32 waves). Per 2048-edge chunk: LDS counting sort by s_local
// (wave-shfl block scan, ~6 barriers), then thread t (= vertex t) walks its
// row, random-reads pvm16 (1x64 B line/edge), accumulates in registers.
// ---------------------------------------------------------------------------
__global__ __launch_bounds__(LT, 8) void lap_sorted_kernel(
    const int2* __restrict__ ewB, const int* __restrict__ boff2,
    const unsigned* __restrict__ pvm16, float* __restrict__ lap) {
  __shared__ int2 eL[CHK];   // 16 KB sorted chunk
  __shared__ int rs[VB2];    // hist -> exclusive rowstart
  __shared__ int cur[VB2];   // scatter cursors
  __shared__ int wsum[8];    // per-wave sums
  int p = blockIdx.x, t = threadIdx.x;
  int lane = t & 63, wid = t >> 6;
  int beg = boff2[p * PBLK];
  int end = (p < NB2 - 1) ? boff2[(p + 1) * PBLK] : E;

  float acc[24];
#pragma unroll
  for (int i = 0; i < 24; ++i) acc[i] = 0.f;

  for (int cbeg = beg; cbeg < end; cbeg += CHK) {
    int cnt = min(CHK, end - cbeg);
    rs[t] = 0;
    __syncthreads();

    // load chunk edges to registers + histogram s_local
    int2 er[CHK / LT];
#pragma unroll
    for (int j = 0; j < CHK / LT; ++j) {
      int idx = j * LT + t;
      if (idx < cnt) {
        er[j] = ewB[cbeg + idx];
        atomicAdd(&rs[((unsigned)er[j].x) >> 18], 1);
      }
    }
    __syncthreads();

    // block exclusive scan of rs[512] via wave shfl
    int x = rs[t];
    int incl = x;
#pragma unroll
    for (int off = 1; off < 64; off <<= 1) {
      int y = __shfl_up(incl, off, 64);
      if (lane >= off) incl += y;
    }
    if (lane == 63) wsum[wid] = incl;
    __syncthreads();
    if (t < 8) {
      int s = wsum[t];
#pragma unroll
      for (int off = 1; off < 8; off <<= 1) {
        int y = __shfl_up(s, off, 64);
        if (t >= off) s += y;
      }
      wsum[t] = s;  // inclusive wave sums
    }
    __syncthreads();
    int wbase = (wid == 0) ? 0 : wsum[wid - 1];
    int excl = incl + wbase - x;
    __syncthreads();  // done reading rs as hist
    rs[t] = excl;
    cur[t] = excl;
    __syncthreads();

    // scatter registered edges into sorted LDS list
#pragma unroll
    for (int j = 0; j < CHK / LT; ++j) {
      int idx = j * LT + t;
      if (idx < cnt) {
        int sl = ((unsigned)er[j].x) >> 18;
        int pos = atomicAdd(&cur[sl], 1);
        eL[pos] = er[j];
      }
    }
    __syncthreads();

    // thread t = vertex t: walk own row, random pvm16 read, reg accumulate
    int rbeg = rs[t];
    int rend = (t < VB2 - 1) ? rs[t + 1] : cnt;
    for (int j = rbeg; j < rend; ++j) {
      int2 ew = eL[j];
      float w = __int_as_float(ew.y);
      int d = ew.x & 0x3ffff;
      const uint4* q = reinterpret_cast<const uint4*>(pvm16 + (size_t)d * 16);
      uint4 q0 = q[0], q1 = q[1], q2 = q[2], q3 = q[3];
      unsigned u[16] = {q0.x, q0.y, q0.z, q0.w, q1.x, q1.y, q1.z, q1.w,
                        q2.x, q2.y, q2.z, q2.w, q3.x, q3.y, q3.z, q3.w};
#pragma unroll
      for (int b = 0; b < B; ++b) {
        acc[b * 3 + 0] += w * bflo(u[2 * b]);
        acc[b * 3 + 1] += w * bfhi(u[2 * b]);
        acc[b * 3 + 2] += w * bflo(u[2 * b + 1]);
      }
    }
    __syncthreads();  // eL/rs reused next chunk
  }

  int v = p * VB2 + t;
#pragma unroll
  for (int b = 0; b < B; ++b) {
    size_t o = ((size_t)b * V + v) * 3;
    lap[o + 0] = acc[b * 3 + 0];
    lap[o + 1] = acc[b * 3 + 1];
    lap[o + 2] = acc[b * 3 + 2];
  }
}

// Tier-C fallback: per-edge atomic scatter.
__global__ __launch_bounds__(256) void lap_atomic_kernel(
    const float* __restrict__ lapw, const int* __restrict__ st,
    const int* __restrict__ ed, const float* __restrict__ posed,
    float* __restrict__ lap) {
  int e = blockIdx.x * blockDim.x + threadIdx.x;
  if (e >= E) return;
  float w = lapw[e];
  int s = st[e];
  int d = ed[e];
#pragma unroll
  for (int b = 0; b < B; ++b) {
    size_t pb = ((size_t)b * V + d) * 3;
    size_t ob = ((size_t)b * V + s) * 3;
    atomicAdd(&lap[ob + 0], w * posed[pb + 0]);
    atomicAdd(&lap[ob + 1], w * posed[pb + 1]);
    atomicAdd(&lap[ob + 2], w * posed[pb + 2]);
  }
}

extern "C" void kernel_launch(void* const* d_in, const int* in_sizes, int n_in,
                              void* d_out, int out_size, void* d_ws, size_t ws_size,
                              hipStream_t stream) {
  const float* tv    = (const float*)d_in[0];
  const float* jquat = (const float*)d_in[1];
  const float* jtran = (const float*)d_in[2];
  const float* sw    = (const float*)d_in[3];
  const float* npos  = (const float*)d_in[4];
  const float* nquat = (const float*)d_in[5];
  const float* ntran = (const float*)d_in[6];
  const float* lw    = (const float*)d_in[7];
  const float* lapw  = (const float*)d_in[8];
  const int*   sidx  = (const int*)d_in[9];
  const int*   lidx  = (const int*)d_in[10];
  const int*   lst   = (const int*)d_in[11];
  const int*   led   = (const int*)d_in[12];
  float* out = (float*)d_out;
  float* lap = out + (size_t)B * V * 3;

  // ---- workspace layout (all offsets 16 B aligned) ----
  float*    jqd   = (float*)d_ws;                       // 4096 f (16 KB)
  float*    nmt   = jqd + 4096;                         // B*G*12 f (786 KB)
  int*      bcnt  = (int*)(nmt + (size_t)B * G * 12);   // NB2*PBLK i (512 KB)
  int*      boff2 = bcnt + NB2 * PBLK;                  // NB2*PBLK i (512 KB)
  int*      bsum  = boff2 + NB2 * PBLK;                 // NB2 i (+pad)
  int2*     ewB   = (int2*)(bsum + NB2 + 60);           // E int2 (14.68 MB)
  unsigned* pvm16 = (unsigned*)(ewB + E);               // V*16 u32 (16.78 MB)
  size_t need = (size_t)((char*)(pvm16 + (size_t)V * 16) - (char*)d_ws);
  int tier = (ws_size >= need) ? 0 : 2;

  jqd_kernel<<<(B * J + 255) / 256, 256, 0, stream>>>(jquat, jtran, jqd);
  nmat_kernel<<<(B * G + 255) / 256, 256, 0, stream>>>(npos, nquat, ntran, nmt);

  if (tier == 0) {
    cnt512_kernel<<<PBLK, 256, 0, stream>>>(lst, bcnt);
    scanA_kernel<<<NB2, 256, 0, stream>>>(bcnt, boff2, bsum);
    scanB_kernel<<<1, NB2, 0, stream>>>(bsum);
    scanC_kernel<<<NB2, 256, 0, stream>>>(boff2, bsum);
    part512_kernel<<<PBLK, 256, 0, stream>>>(lst, led, lapw, boff2, ewB);
    posed5_kernel<<<V / PT5, PT5, G * 3 * sizeof(float4), stream>>>(
        tv, sw, lw, sidx, lidx, nmt, jqd, out, pvm16, 0);
    lap_sorted_kernel<<<NB2, LT, 0, stream>>>(ewB, boff2, pvm16, lap);
  } else {
    posed5_kernel<<<V / PT5, PT5, G * 3 * sizeof(float4), stream>>>(
        tv, sw, lw, sidx, lidx, nmt, jqd, out, (unsigned*)jqd /*unused*/, 2);
    lap_atomic_kernel<<<E / 256, 256, 0, stream>>>(lapw, lst, led, out, lap);
  }
}

// Round 16
// 155.749 us; speedup vs baseline: 1.4259x; 1.1289x over previous
//
#include <hip/hip_runtime.h>
#include <hip/hip_bf16.h>
#include <math.h>

// Problem constants (fixed by the reference setup)
constexpr int B = 8;
constexpr int V = 262144;
constexpr int J = 64;
constexpr int K = 4;
constexpr int G = 2048;
constexpr int L = 8;
constexpr int E = 1835008;
constexpr float EPS = 1e-8f;
constexpr int PT5 = 1024;      // posed block size (16 waves, 1 block/CU)
constexpr int NB2 = 256;       // fine buckets (1024 vertices each)
constexpr int VB2 = V / NB2;   // 1024
constexpr int PBLK = 256;      // partition blocks
constexpr int EPP = E / PBLK;  // 7168 edges per partition block
constexpr int CHK = 4096;      // lap_sorted chunk size (edges)
constexpr int JQO = G * 3;     // float4 index of jq planes in posed LDS
// posed LDS: G*3 float4 node table + 1024 float4 jq planes = 114688 B

__device__ inline unsigned bf16bits(float x) {
  unsigned u = __float_as_uint(x);
  return (u + 0x7fffu + ((u >> 16) & 1u)) >> 16;  // round-to-nearest-even
}
__device__ inline float bflo(unsigned u) { return __uint_as_float(u << 16); }
__device__ inline float bfhi(unsigned u) {
  return __uint_as_float(u & 0xffff0000u);
}

// ---------------------------------------------------------------------------
// Kernel 0: per (b,j) normalized joint quat + dual part, written as PLANES:
// qf plane (float4) at ws[0..B*J), df plane at ws[B*J..2*B*J).
// ---------------------------------------------------------------------------
__global__ __launch_bounds__(256) void jqd_kernel(
    const float* __restrict__ jquat, const float* __restrict__ jtrans,
    float* __restrict__ ws) {
  int i = blockIdx.x * blockDim.x + threadIdx.x;
  if (i >= B * J) return;
  float qw = jquat[i * 4 + 0];
  float qx = jquat[i * 4 + 1];
  float qy = jquat[i * 4 + 2];
  float qz = jquat[i * 4 + 3];
  float inv = 1.0f / (sqrtf(qw * qw + qx * qx + qy * qy + qz * qz) + EPS);
  qw *= inv; qx *= inv; qy *= inv; qz *= inv;
  float tx = jtrans[i * 3 + 0];
  float ty = jtrans[i * 3 + 1];
  float tz = jtrans[i * 3 + 2];
  float dw = -0.5f * (tx * qx + ty * qy + tz * qz);
  float dx = 0.5f * (qw * tx + (ty * qz - tz * qy));
  float dy = 0.5f * (qw * ty + (tz * qx - tx * qz));
  float dz = 0.5f * (qw * tz + (tx * qy - ty * qx));
  float4* qfp = reinterpret_cast<float4*>(ws);
  float4* dfp = qfp + B * J;
  qfp[i] = make_float4(qw, qx, qy, qz);
  dfp[i] = make_float4(dw, dx, dy, dz);
}

// ---------------------------------------------------------------------------
// Kernel 0b: per (b,g) affine transform, packed [G][3]float4 per batch (f32).
// warped = M*p + T, T = gp + nt - M*gp. Row r = float4 {m_r0,m_r1,m_r2,t_r}.
// ---------------------------------------------------------------------------
__global__ __launch_bounds__(256) void nmat_kernel(
    const float* __restrict__ npos, const float* __restrict__ nquat,
    const float* __restrict__ ntrans, float* __restrict__ nmt) {
  int i = blockIdx.x * blockDim.x + threadIdx.x;
  if (i >= B * G) return;
  int g = i & (G - 1);
  float4 q = *reinterpret_cast<const float4*>(nquat + (size_t)i * 4);
  float qw = q.x, qx = q.y, qy = q.z, qz = q.w;
  float inv = 1.0f / (sqrtf(qw * qw + qx * qx + qy * qy + qz * qz) + EPS);
  qw *= inv; qx *= inv; qy *= inv; qz *= inv;
  float xx = qx * qx, yy = qy * qy, zz = qz * qz;
  float xy = qx * qy, xz = qx * qz, yz = qy * qz;
  float wx = qw * qx, wy = qw * qy, wz = qw * qz;
  float m00 = 1.f - 2.f * (yy + zz), m01 = 2.f * (xy - wz), m02 = 2.f * (xz + wy);
  float m10 = 2.f * (xy + wz), m11 = 1.f - 2.f * (xx + zz), m12 = 2.f * (yz - wx);
  float m20 = 2.f * (xz - wy), m21 = 2.f * (yz + wx), m22 = 1.f - 2.f * (xx + yy);
  float gx = npos[g * 3 + 0], gy = npos[g * 3 + 1], gz = npos[g * 3 + 2];
  float tx = ntrans[(size_t)i * 3 + 0] + gx - (m00 * gx + m01 * gy + m02 * gz);
  float ty = ntrans[(size_t)i * 3 + 1] + gy - (m10 * gx + m11 * gy + m12 * gz);
  float tz = ntrans[(size_t)i * 3 + 2] + gz - (m20 * gx + m21 * gy + m22 * gz);
  float4* o = reinterpret_cast<float4*>(nmt + (size_t)i * 12);
  o[0] = make_float4(m00, m01, m02, tx);
  o[1] = make_float4(m10, m11, m12, ty);
  o[2] = make_float4(m20, m21, m22, tz);
}

// ---------------------------------------------------------------------------
// posed5b — LDS-staged f32 node table (96 KB, restaged per batch) PLUS the
// full jq planes (16 KB, staged once). All gathers are ds_read_b128; the
// divergent L1 jqd gather (≈1 lane-req/cyc TA serialization) is gone.
// mode: 0 = write pvm16, 2 = no pvm16 + zero lap
// ---------------------------------------------------------------------------
__global__ __launch_bounds__(PT5) void posed5b_kernel(
    const float* __restrict__ tv, const float* __restrict__ sw_in,
    const float* __restrict__ lw_in, const int* __restrict__ sidx,
    const int* __restrict__ lidx, const float* __restrict__ nmt,
    const float* __restrict__ jqd, float* __restrict__ out,
    unsigned* __restrict__ pvm16, int mode) {
  extern __shared__ float4 sm4[];  // (G*3 + 1024) float4 = 114688 B
  int t = threadIdx.x;
  int v = blockIdx.x * PT5 + t;

  // stage jq planes once (1024 float4 = one per thread)
  sm4[JQO + t] = reinterpret_cast<const float4*>(jqd)[t];

  float px = tv[(size_t)v * 3 + 0];
  float py = tv[(size_t)v * 3 + 1];
  float pz = tv[(size_t)v * 3 + 2];

  int4 si = *reinterpret_cast<const int4*>(sidx + (size_t)v * 4);
  float4 swv = *reinterpret_cast<const float4*>(sw_in + (size_t)v * 4);
  int4 li0 = *reinterpret_cast<const int4*>(lidx + (size_t)v * 8);
  int4 li1 = *reinterpret_cast<const int4*>(lidx + (size_t)v * 8 + 4);
  float4 lw0 = *reinterpret_cast<const float4*>(lw_in + (size_t)v * 8);
  float4 lw1 = *reinterpret_cast<const float4*>(lw_in + (size_t)v * 8 + 4);

  float sinv = 1.0f / (swv.x + swv.y + swv.z + swv.w + EPS);
  float swn[K] = {swv.x * sinv, swv.y * sinv, swv.z * sinv, swv.w * sinv};
  int sj[K] = {si.x, si.y, si.z, si.w};

  float linv =
      1.0f / (lw0.x + lw0.y + lw0.z + lw0.w + lw1.x + lw1.y + lw1.z + lw1.w + EPS);
  float lwn[L] = {lw0.x * linv, lw0.y * linv, lw0.z * linv, lw0.w * linv,
                  lw1.x * linv, lw1.y * linv, lw1.z * linv, lw1.w * linv};
  int gi[L] = {li0.x * 3, li0.y * 3, li0.z * 3, li0.w * 3,
               li1.x * 3, li1.y * 3, li1.z * 3, li1.w * 3};

  constexpr size_t LAPOFF = (size_t)B * V * 3;
  unsigned pk[2 * B];

  for (int b = 0; b < B; ++b) {
    __syncthreads();  // previous batch's reads done before restage
    const float4* src = reinterpret_cast<const float4*>(nmt + (size_t)b * G * 12);
#pragma unroll
    for (int it = 0; it < (G * 3) / PT5; ++it) {
      int q = it * PT5 + t;
      sm4[q] = src[q];
    }
    __syncthreads();

    // ---- v_eg = sum_l lw * (M p + T); 3x ds_read_b128 per link ----
    float ex = 0.f, ey = 0.f, ez = 0.f;
#pragma unroll
    for (int l = 0; l < L; ++l) {
      float4 r0 = sm4[gi[l] + 0];
      float4 r1 = sm4[gi[l] + 1];
      float4 r2 = sm4[gi[l] + 2];
      float w = lwn[l];
      ex += w * (r0.x * px + r0.y * py + r0.z * pz + r0.w);
      ey += w * (r1.x * px + r1.y * py + r1.z * pz + r1.w);
      ez += w * (r2.x * px + r2.y * py + r2.z * pz + r2.w);
    }

    // ---- joint dual-quat blend from LDS jq planes (2x b128 per k) ----
    float rbw = 0.f, rbx = 0.f, rby = 0.f, rbz = 0.f;
    float dbw = 0.f, dbx = 0.f, dby = 0.f, dbz = 0.f;
    float r0w = 0.f, r0x = 0.f, r0y = 0.f, r0z = 0.f;
#pragma unroll
    for (int k = 0; k < K; ++k) {
      float4 qf = sm4[JQO + (b << 6) + sj[k]];
      float4 df = sm4[JQO + 512 + (b << 6) + sj[k]];
      float qw = qf.x, qx = qf.y, qy = qf.z, qz = qf.w;
      if (k == 0) { r0w = qw; r0x = qx; r0y = qy; r0z = qz; }
      float dotr = qw * r0w + qx * r0x + qy * r0y + qz * r0z;
      float s = (dotr >= 0.0f) ? swn[k] : -swn[k];
      rbw += s * qw; rbx += s * qx; rby += s * qy; rbz += s * qz;
      dbw += s * df.x; dbx += s * df.y; dby += s * df.z; dbz += s * df.w;
    }
    float ninv = 1.0f / (sqrtf(rbw * rbw + rbx * rbx + rby * rby + rbz * rbz) + EPS);
    rbw *= ninv; rbx *= ninv; rby *= ninv; rbz *= ninv;
    dbw *= ninv; dbx *= ninv; dby *= ninv; dbz *= ninv;

    float txx = 2.0f * (rbw * dbx - dbw * rbx + (rby * dbz - rbz * dby));
    float tyy = 2.0f * (rbw * dby - dbw * rby + (rbz * dbx - rbx * dbz));
    float tzz = 2.0f * (rbw * dbz - dbw * rbz + (rbx * dby - rby * dbx));

    float cx = rby * ez - rbz * ey + rbw * ex;
    float cy = rbz * ex - rbx * ez + rbw * ey;
    float cz = rbx * ey - rby * ex + rbw * ez;
    float ox = ex + 2.0f * (rby * cz - rbz * cy) + txx;
    float oy = ey + 2.0f * (rbz * cx - rbx * cz) + tyy;
    float oz = ez + 2.0f * (rbx * cy - rby * cx) + tzz;

    size_t o = ((size_t)b * V + v) * 3;
    out[o + 0] = ox; out[o + 1] = oy; out[o + 2] = oz;
    pk[b * 2 + 0] = bf16bits(ox) | (bf16bits(oy) << 16);
    pk[b * 2 + 1] = bf16bits(oz);
    if (mode == 2) {
      out[LAPOFF + o + 0] = 0.f;
      out[LAPOFF + o + 1] = 0.f;
      out[LAPOFF + o + 2] = 0.f;
    }
  }

  if (mode == 0) {
    uint4* dst = reinterpret_cast<uint4*>(pvm16 + (size_t)v * 16);
    dst[0] = make_uint4(pk[0], pk[1], pk[2], pk[3]);
    dst[1] = make_uint4(pk[4], pk[5], pk[6], pk[7]);
    dst[2] = make_uint4(pk[8], pk[9], pk[10], pk[11]);
    dst[3] = make_uint4(pk[12], pk[13], pk[14], pk[15]);
  }
}

// ---------------------------------------------------------------------------
// 256-way edge partition (R11-proven). Bucket = st >> 10 (1024 verts each).
// Payload packs s_local(10b) | d(18b) into one int + weight.
// ---------------------------------------------------------------------------
__global__ __launch_bounds__(256) void cnt256_kernel(const int* __restrict__ st,
                                                     int* __restrict__ bcnt) {
  __shared__ int h[NB2];
  int blk = blockIdx.x, t = threadIdx.x;
  h[t] = 0;
  __syncthreads();
  int e0 = blk * EPP;
  for (int i = e0 + t; i < e0 + EPP; i += 256) atomicAdd(&h[st[i] >> 10], 1);
  __syncthreads();
  bcnt[t * PBLK + blk] = h[t];  // bucket-major
}

__global__ __launch_bounds__(256) void scanA_kernel(const int* __restrict__ in,
                                                    int* __restrict__ out,
                                                    int* __restrict__ bs) {
  __shared__ int s[256];
  int t = threadIdx.x;
  int i = blockIdx.x * 256 + t;
  int x = in[i];
  s[t] = x;
  __syncthreads();
  for (int off = 1; off < 256; off <<= 1) {
    int v = (t >= off) ? s[t - off] : 0;
    __syncthreads();
    s[t] += v;
    __syncthreads();
  }
  out[i] = s[t] - x;
  if (t == 255) bs[blockIdx.x] = s[t];
}

__global__ __launch_bounds__(256) void scanB_kernel(int* __restrict__ bs) {
  __shared__ int s[256];
  int t = threadIdx.x;
  int x = bs[t];
  s[t] = x;
  __syncthreads();
  for (int off = 1; off < 256; off <<= 1) {
    int v = (t >= off) ? s[t - off] : 0;
    __syncthreads();
    s[t] += v;
    __syncthreads();
  }
  bs[t] = s[t] - x;
}

__global__ __launch_bounds__(256) void scanC_kernel(int* __restrict__ out,
                                                    const int* __restrict__ bs) {
  out[blockIdx.x * 256 + threadIdx.x] += bs[blockIdx.x];
}

__global__ __launch_bounds__(256) void part256_kernel(
    const int* __restrict__ st, const int* __restrict__ ed,
    const float* __restrict__ w, const int* __restrict__ boff2,
    int2* __restrict__ ewB) {
  __shared__ int lbase[NB2];
  __shared__ int lcur[NB2];
  int blk = blockIdx.x, t = threadIdx.x;
  lbase[t] = boff2[t * PBLK + blk];
  lcur[t] = 0;
  __syncthreads();
  int e0 = blk * EPP;
  for (int i = e0 + t; i < e0 + EPP; i += 256) {
    int s = st[i];
    int b = s >> 10;
    int pos = lbase[b] + atomicAdd(&lcur[b], 1);
    ewB[pos] = make_int2(((s & 1023) << 18) | ed[i], __float_as_int(w[i]));
  }
}

// ---------------------------------------------------------------------------
// lap_sorted (R11-proven): one 1024-thread block per 1024-vertex bucket.
// Per 4096-edge chunk: LDS counting sort by s_local, then thread t = vertex t
// walks its row, random-reads pvm16 (1x64 B line/edge), reg accumulate.
// ---------------------------------------------------------------------------
__global__ __launch_bounds__(1024) void lap_sorted_kernel(
    const int2* __restrict__ ewB, const int* __restrict__ boff2,
    const unsigned* __restrict__ pvm16, float* __restrict__ lap) {
  __shared__ int2 eL[CHK];     // 32 KB sorted chunk
  __shared__ int rs[VB2];      // hist -> inclusive -> exclusive rowstart
  __shared__ int cur[VB2];     // scatter cursors
  int p = blockIdx.x, t = threadIdx.x;
  int beg = boff2[p * PBLK];
  int end = (p < NB2 - 1) ? boff2[(p + 1) * PBLK] : E;

  float acc[24];
#pragma unroll
  for (int i = 0; i < 24; ++i) acc[i] = 0.f;

  for (int cbeg = beg; cbeg < end; cbeg += CHK) {
    int cnt = min(CHK, end - cbeg);
    rs[t] = 0;
    __syncthreads();

    int2 er[CHK / 1024];
#pragma unroll
    for (int j = 0; j < CHK / 1024; ++j) {
      int idx = j * 1024 + t;
      if (idx < cnt) {
        er[j] = ewB[cbeg + idx];
        atomicAdd(&rs[((unsigned)er[j].x) >> 18], 1);
      }
    }
    __syncthreads();

    int x = rs[t];
    for (int off = 1; off < VB2; off <<= 1) {
      int v = (t >= off) ? rs[t - off] : 0;
      __syncthreads();
      rs[t] += v;
      __syncthreads();
    }
    int excl = rs[t] - x;
    __syncthreads();
    rs[t] = excl;
    cur[t] = excl;
    __syncthreads();

#pragma unroll
    for (int j = 0; j < CHK / 1024; ++j) {
      int idx = j * 1024 + t;
      if (idx < cnt) {
        int sl = ((unsigned)er[j].x) >> 18;
        int pos = atomicAdd(&cur[sl], 1);
        eL[pos] = er[j];
      }
    }
    __syncthreads();

    int rbeg = rs[t];
    int rend = (t < VB2 - 1) ? rs[t + 1] : cnt;
    for (int j = rbeg; j < rend; ++j) {
      int2 ew = eL[j];
      float w = __int_as_float(ew.y);
      int d = ew.x & 0x3ffff;
      const uint4* q = reinterpret_cast<const uint4*>(pvm16 + (size_t)d * 16);
      uint4 q0 = q[0], q1 = q[1], q2 = q[2], q3 = q[3];
      unsigned u[16] = {q0.x, q0.y, q0.z, q0.w, q1.x, q1.y, q1.z, q1.w,
                        q2.x, q2.y, q2.z, q2.w, q3.x, q3.y, q3.z, q3.w};
#pragma unroll
      for (int b = 0; b < B; ++b) {
        acc[b * 3 + 0] += w * bflo(u[2 * b]);
        acc[b * 3 + 1] += w * bfhi(u[2 * b]);
        acc[b * 3 + 2] += w * bflo(u[2 * b + 1]);
      }
    }
    __syncthreads();  // eL/rs reused next chunk
  }

  int v = p * VB2 + t;
#pragma unroll
  for (int b = 0; b < B; ++b) {
    size_t o = ((size_t)b * V + v) * 3;
    lap[o + 0] = acc[b * 3 + 0];
    lap[o + 1] = acc[b * 3 + 1];
    lap[o + 2] = acc[b * 3 + 2];
  }
}

// Tier-C fallback: per-edge atomic scatter.
__global__ __launch_bounds__(256) void lap_atomic_kernel(
    const float* __restrict__ lapw, const int* __restrict__ st,
    const int* __restrict__ ed, const float* __restrict__ posed,
    float* __restrict__ lap) {
  int e = blockIdx.x * blockDim.x + threadIdx.x;
  if (e >= E) return;
  float w = lapw[e];
  int s = st[e];
  int d = ed[e];
#pragma unroll
  for (int b = 0; b < B; ++b) {
    size_t pb = ((size_t)b * V + d) * 3;
    size_t ob = ((size_t)b * V + s) * 3;
    atomicAdd(&lap[ob + 0], w * posed[pb + 0]);
    atomicAdd(&lap[ob + 1], w * posed[pb + 1]);
    atomicAdd(&lap[ob + 2], w * posed[pb + 2]);
  }
}

extern "C" void kernel_launch(void* const* d_in, const int* in_sizes, int n_in,
                              void* d_out, int out_size, void* d_ws, size_t ws_size,
                              hipStream_t stream) {
  const float* tv    = (const float*)d_in[0];
  const float* jquat = (const float*)d_in[1];
  const float* jtran = (const float*)d_in[2];
  const float* sw    = (const float*)d_in[3];
  const float* npos  = (const float*)d_in[4];
  const float* nquat = (const float*)d_in[5];
  const float* ntran = (const float*)d_in[6];
  const float* lw    = (const float*)d_in[7];
  const float* lapw  = (const float*)d_in[8];
  const int*   sidx  = (const int*)d_in[9];
  const int*   lidx  = (const int*)d_in[10];
  const int*   lst   = (const int*)d_in[11];
  const int*   led   = (const int*)d_in[12];
  float* out = (float*)d_out;
  float* lap = out + (size_t)B * V * 3;

  // ---- workspace layout (all offsets 16 B aligned) ----
  float*    jqd   = (float*)d_ws;                       // 4096 f (16 KB, planes)
  float*    nmt   = jqd + 4096;                         // B*G*12 f (786 KB)
  int*      bcnt  = (int*)(nmt + (size_t)B * G * 12);   // NB2*PBLK i (256 KB)
  int*      boff2 = bcnt + NB2 * PBLK;                  // NB2*PBLK i (256 KB)
  int*      bsum  = boff2 + NB2 * PBLK;                 // NB2 i (+pad)
  int2*     ewB   = (int2*)(bsum + NB2 + 60);           // E int2 (14.68 MB)
  unsigned* pvm16 = (unsigned*)(ewB + E);               // V*16 u32 (16.78 MB)
  size_t need = (size_t)((char*)(pvm16 + (size_t)V * 16) - (char*)d_ws);
  int tier = (ws_size >= need) ? 0 : 2;

  constexpr size_t POSED_LDS = (size_t)(G * 3 + 1024) * sizeof(float4);

  jqd_kernel<<<(B * J + 255) / 256, 256, 0, stream>>>(jquat, jtran, jqd);
  nmat_kernel<<<(B * G + 255) / 256, 256, 0, stream>>>(npos, nquat, ntran, nmt);

  if (tier == 0) {
    cnt256_kernel<<<PBLK, 256, 0, stream>>>(lst, bcnt);
    scanA_kernel<<<NB2, 256, 0, stream>>>(bcnt, boff2, bsum);
    scanB_kernel<<<1, 256, 0, stream>>>(bsum);
    scanC_kernel<<<NB2, 256, 0, stream>>>(boff2, bsum);
    part256_kernel<<<PBLK, 256, 0, stream>>>(lst, led, lapw, boff2, ewB);
    posed5b_kernel<<<V / PT5, PT5, POSED_LDS, stream>>>(
        tv, sw, lw, sidx, lidx, nmt, jqd, out, pvm16, 0);
    lap_sorted_kernel<<<NB2, 1024, 0, stream>>>(ewB, boff2, pvm16, lap);
  } else {
    posed5b_kernel<<<V / PT5, PT5, POSED_LDS, stream>>>(
        tv, sw, lw, sidx, lidx, nmt, jqd, out, (unsigned*)jqd /*unused*/, 2);
    lap_atomic_kernel<<<E / 256, 256, 0, stream>>>(lapw, lst, led, out, lap);
  }
}